// Round 1
// baseline (3462.943 us; speedup 1.0000x reference)
//
#include <hip/hip_runtime.h>
#include <hip/hip_bf16.h>

typedef _Float16 f16;
typedef _Float16 f16x8 __attribute__((ext_vector_type(8)));
typedef _Float16 f16x4 __attribute__((ext_vector_type(4)));
typedef float f32x4 __attribute__((ext_vector_type(4)));

#define B_ 64
#define T_ 32
#define L_ 49
#define F_ 512
#define H_ 512
#define A_ 256
#define E_ 256
#define V_ 32000
#define G4 2048   // 4*H

// ---------------------------------------------------------------- converts
__global__ void k_cvt_f16(const float* __restrict__ x, f16* __restrict__ y, int n4) {
    int i = blockIdx.x * 256 + threadIdx.x;
    if (i < n4) {
        float4 v = ((const float4*)x)[i];
        f16x4 h = {(f16)v.x, (f16)v.y, (f16)v.z, (f16)v.w};
        ((f16x4*)y)[i] = h;
    }
}

// embedding gather -> fp16, row r = b*T + t
__global__ void k_emb(const float* __restrict__ emb, const int* __restrict__ cap,
                      f16* __restrict__ out) {
    int r = blockIdx.x;
    int tok = cap[r];
    out[(size_t)r * E_ + threadIdx.x] = (f16)emb[(size_t)tok * E_ + threadIdx.x];
}

// ---------------------------------------------------------------- init h0/c0
__global__ void k_init(const float* __restrict__ feats,
                       const float* __restrict__ Wh, const float* __restrict__ bh,
                       const float* __restrict__ Wc, const float* __restrict__ bc,
                       float* __restrict__ hbuf, f16* __restrict__ h16rec,
                       float* __restrict__ c_cur) {
    __shared__ float mean[F_];
    int b = blockIdx.x, tid = threadIdx.x;
    for (int f = tid; f < F_; f += 256) {
        float s = 0.f;
        for (int l = 0; l < L_; ++l) s += feats[((size_t)b * L_ + l) * F_ + f];
        mean[f] = s * (1.f / 49.f);
    }
    __syncthreads();
    for (int h = tid; h < H_; h += 256) {
        float a = bh[h], c = bc[h];
        for (int k = 0; k < F_; ++k) {
            float m = mean[k];
            a += m * Wh[k * H_ + h];
            c += m * Wc[k * H_ + h];
        }
        hbuf[b * H_ + h] = a;
        h16rec[b * H_ + h] = (f16)a;
        c_cur[b * H_ + h] = c;
    }
}

// ---------------------------------------------------------------- feat_proj (fp32)
// out[row, a] = dot(feats[row,:], W_feat[:,a]) + b_feat[a]; rows = B*L = 3136
__global__ void k_featproj(const float* __restrict__ feats, const float* __restrict__ Wf,
                           const float* __restrict__ bf, float* __restrict__ out) {
    __shared__ float fs[16][F_];
    int r0 = blockIdx.x * 16, tid = threadIdx.x;
    for (int i = tid; i < 16 * F_; i += 256)
        fs[i >> 9][i & 511] = feats[(size_t)r0 * F_ + i];
    __syncthreads();
    float acc[16];
#pragma unroll
    for (int r = 0; r < 16; ++r) acc[r] = 0.f;
    for (int k = 0; k < F_; ++k) {
        float w = Wf[k * A_ + tid];
#pragma unroll
        for (int r = 0; r < 16; ++r) acc[r] += fs[r][k] * w;
    }
    float bb = bf[tid];
#pragma unroll
    for (int r = 0; r < 16; ++r) out[(size_t)(r0 + r) * A_ + tid] = acc[r] + bb;
}

// ---------------------------------------------------------------- fp16 MFMA GEMM
// C(MxN,f32) = A(MxK,f16,row-major) @ B(KxN,f16,row-major) [+bias0+bias1]
// BM=BN=64, BK=32; 256 threads = 4 waves, each wave a 32x32 quadrant (2x2 mfma 16x16x32)
struct GemmSmem {
    f16 As[64][40];   // [row][k]   (+8 pad)
    f16 Bs[64][40];   // [col][k]   transposed (+8 pad)
};

__device__ __forceinline__ void gemm_tile(const f16* __restrict__ A, int lda,
                                          const f16* __restrict__ B, int ldb,
                                          float* __restrict__ C, int ldc, int K,
                                          int m0, int n0,
                                          const float* __restrict__ bias0,
                                          const float* __restrict__ bias1,
                                          GemmSmem* sm) {
    int tid = threadIdx.x;
    int lane = tid & 63, wave = tid >> 6;
    int wr = (wave >> 1) * 32, wc = (wave & 1) * 32;
    f32x4 acc[2][2];
#pragma unroll
    for (int i = 0; i < 2; ++i)
#pragma unroll
        for (int j = 0; j < 2; ++j) {
            acc[i][j][0] = 0.f; acc[i][j][1] = 0.f; acc[i][j][2] = 0.f; acc[i][j][3] = 0.f;
        }
    int r_a = tid >> 2, k_a = (tid & 3) * 8;   // A-tile staging coords
    int k_b = tid >> 3, n_b = (tid & 7) * 8;   // B-tile staging coords
    int frow = lane & 15, fk = (lane >> 4) * 8;

    for (int k0 = 0; k0 < K; k0 += 32) {
        __syncthreads();
        *(f16x8*)&sm->As[r_a][k_a] = *(const f16x8*)&A[(size_t)(m0 + r_a) * lda + k0 + k_a];
        f16x8 bv = *(const f16x8*)&B[(size_t)(k0 + k_b) * ldb + n0 + n_b];
#pragma unroll
        for (int j = 0; j < 8; ++j) sm->Bs[n_b + j][k_b] = bv[j];
        __syncthreads();
#pragma unroll
        for (int mi = 0; mi < 2; ++mi) {
            f16x8 av = *(f16x8*)&sm->As[wr + mi * 16 + frow][fk];
#pragma unroll
            for (int ni = 0; ni < 2; ++ni) {
                f16x8 bvf = *(f16x8*)&sm->Bs[wc + ni * 16 + frow][fk];
                acc[mi][ni] = __builtin_amdgcn_mfma_f32_16x16x32_f16(av, bvf, acc[mi][ni], 0, 0, 0);
            }
        }
    }
    int rq = (lane >> 4) * 4;
#pragma unroll
    for (int mi = 0; mi < 2; ++mi)
#pragma unroll
        for (int ni = 0; ni < 2; ++ni) {
            int cc = n0 + wc + ni * 16 + frow;
            float badd = (bias0 ? bias0[cc] : 0.f) + (bias1 ? bias1[cc] : 0.f);
#pragma unroll
            for (int r = 0; r < 4; ++r) {
                int rr = m0 + wr + mi * 16 + rq + r;
                C[(size_t)rr * ldc + cc] = acc[mi][ni][r] + badd;
            }
        }
}

__global__ void k_gemm(const f16* __restrict__ A, int lda, const f16* __restrict__ B, int ldb,
                       float* __restrict__ C, int ldc, int K, int ntn,
                       const float* __restrict__ bias0, const float* __restrict__ bias1) {
    __shared__ GemmSmem sm;
    int m0 = (blockIdx.x / ntn) * 64, n0 = (blockIdx.x % ntn) * 64;
    gemm_tile(A, lda, B, ldb, C, ldc, K, m0, n0, bias0, bias1, &sm);
}

// ---------------------------------------------------------------- step phase A
// wg < 64 : attention for batch b (fp32)  |  wg 64..95 : hWhh MFMA N-tile
__global__ void k_step_a(int t,
                         const float* __restrict__ hbuf, const f16* __restrict__ h16rec,
                         const f16* __restrict__ Whh16,
                         const float* __restrict__ featproj,
                         const float* __restrict__ Whid, const float* __restrict__ bhid,
                         const float* __restrict__ Wscore, const float* __restrict__ bscore,
                         float* __restrict__ alpha_ws, float* __restrict__ out_alpha,
                         float* __restrict__ hWhh) {
    __shared__ GemmSmem sm;
    int wg = blockIdx.x, tid = threadIdx.x;
    if (wg >= 64) {
        int n0 = (wg - 64) * 64;
        gemm_tile(h16rec + (size_t)t * B_ * H_, H_, Whh16, G4, hWhh, G4, H_,
                  0, n0, nullptr, nullptr, &sm);
        return;
    }
    float* h_s = (float*)&sm;            // 512
    float* ea  = h_s + H_;               // 256
    float* sc  = ea + A_;                // 52
    int b = wg;
    const float* h = hbuf + (size_t)t * B_ * H_ + (size_t)b * H_;
    for (int i = tid; i < H_; i += 256) h_s[i] = h[i];
    __syncthreads();
    {
        float acc = bhid[tid];
        for (int k = 0; k < H_; ++k) acc += h_s[k] * Whid[k * A_ + tid];
        ea[tid] = acc;
    }
    __syncthreads();
    int wv = tid >> 6, ln = tid & 63;
    for (int l = wv; l < L_; l += 4) {
        float p = 0.f;
        const float* fp = featproj + ((size_t)b * L_ + l) * A_;
        for (int j = ln; j < A_; j += 64) p += tanhf(fp[j] + ea[j]) * Wscore[j];
#pragma unroll
        for (int off = 32; off > 0; off >>= 1) p += __shfl_xor(p, off);
        if (ln == 0) sc[l] = p;
    }
    __syncthreads();
    if (tid < 64) {
        float v = (tid < L_) ? sc[tid] + bscore[0] : -3.4e38f;
        float m = v;
#pragma unroll
        for (int off = 32; off > 0; off >>= 1) m = fmaxf(m, __shfl_xor(m, off));
        float e = (tid < L_) ? expf(v - m) : 0.f;
        float s = e;
#pragma unroll
        for (int off = 32; off > 0; off >>= 1) s += __shfl_xor(s, off);
        if (tid < L_) {
            float al = e / s;
            alpha_ws[b * L_ + tid] = al;
            out_alpha[((size_t)b * T_ + t) * L_ + tid] = al;
        }
    }
}

// ---------------------------------------------------------------- step phase B
// gates = embproj[b,t] + hWhh[b] + sum_l alpha[b,l]*featproj2[b,l]; LSTM pointwise
__global__ void k_step_b(int t,
                         const float* __restrict__ embproj, const float* __restrict__ hWhh,
                         const float* __restrict__ alpha_ws, const float* __restrict__ featproj2,
                         float* __restrict__ c_cur, float* __restrict__ hbuf,
                         f16* __restrict__ h16rec, f16* __restrict__ h16log) {
    __shared__ float al[L_];
    int b = blockIdx.x >> 1, jh = blockIdx.x & 1;
    int tid = threadIdx.x;
    if (tid < L_) al[tid] = alpha_ws[b * L_ + tid];
    __syncthreads();
    int j = jh * 256 + tid;
    size_t eb = ((size_t)b * T_ + t) * G4 + j;
    float gi = embproj[eb], gf = embproj[eb + 512], gg = embproj[eb + 1024], go = embproj[eb + 1536];
    size_t wb = (size_t)b * G4 + j;
    gi += hWhh[wb]; gf += hWhh[wb + 512]; gg += hWhh[wb + 1024]; go += hWhh[wb + 1536];
    for (int l = 0; l < L_; ++l) {
        float a = al[l];
        const float* fp = featproj2 + ((size_t)b * L_ + l) * G4 + j;
        gi += a * fp[0]; gf += a * fp[512]; gg += a * fp[1024]; go += a * fp[1536];
    }
    float ii = 1.f / (1.f + expf(-gi));
    float ff = 1.f / (1.f + expf(-gf));
    float oo = 1.f / (1.f + expf(-go));
    float g = tanhf(gg);
    int cidx = b * H_ + j;
    float c = ff * c_cur[cidx] + ii * g;
    float hh = oo * tanhf(c);
    c_cur[cidx] = c;
    hbuf[(size_t)(t + 1) * B_ * H_ + cidx] = hh;
    f16 h6 = (f16)hh;
    h16rec[(size_t)(t + 1) * B_ * H_ + cidx] = h6;
    h16log[((size_t)b * T_ + t) * H_ + j] = h6;
}

// ---------------------------------------------------------------- launch
extern "C" void kernel_launch(void* const* d_in, const int* in_sizes, int n_in,
                              void* d_out, int out_size, void* d_ws, size_t ws_size,
                              hipStream_t stream) {
    const float* image_feats = (const float*)d_in[0];
    const int*   caption     = (const int*)d_in[1];
    const float* embedding   = (const float*)d_in[2];
    const float* W_init_h    = (const float*)d_in[3];
    const float* b_init_h    = (const float*)d_in[4];
    const float* W_init_c    = (const float*)d_in[5];
    const float* b_init_c    = (const float*)d_in[6];
    const float* W_feat      = (const float*)d_in[7];
    const float* b_feat      = (const float*)d_in[8];
    const float* W_hid       = (const float*)d_in[9];
    const float* b_hid       = (const float*)d_in[10];
    const float* W_score     = (const float*)d_in[11];
    const float* b_score     = (const float*)d_in[12];
    const float* W_ih        = (const float*)d_in[13];
    const float* b_ih        = (const float*)d_in[14];
    const float* W_hh        = (const float*)d_in[15];
    const float* b_hh        = (const float*)d_in[16];
    const float* W_out       = (const float*)d_in[17];
    const float* b_out       = (const float*)d_in[18];

    float* preds = (float*)d_out;                                   // (B,T,V)
    float* out_alpha = preds + (size_t)B_ * T_ * V_;                // (B,T,L)

    size_t off = 0;
    char* base = (char*)d_ws;
    auto carve = [&](size_t bytes) {
        void* p = base + off;
        off += (bytes + 255) & ~(size_t)255;
        return p;
    };
    float* featproj2 = (float*)carve((size_t)B_ * L_ * G4 * 4);     // 25.7 MB
    float* embproj   = (float*)carve((size_t)B_ * T_ * G4 * 4);     // 16.8 MB
    float* featproj  = (float*)carve((size_t)B_ * L_ * A_ * 4);     // 3.2 MB
    float* hbuf      = (float*)carve((size_t)(T_ + 1) * B_ * H_ * 4);
    float* c_cur     = (float*)carve((size_t)B_ * H_ * 4);
    float* hWhh      = (float*)carve((size_t)B_ * G4 * 4);
    float* alpha_ws  = (float*)carve((size_t)B_ * L_ * 4);
    f16* feats16     = (f16*)carve((size_t)B_ * L_ * F_ * 2);
    f16* embs16      = (f16*)carve((size_t)B_ * T_ * E_ * 2);
    f16* Wih16       = (f16*)carve((size_t)(E_ + F_) * G4 * 2);
    f16* Whh16       = (f16*)carve((size_t)H_ * G4 * 2);
    f16* Wout16      = (f16*)carve((size_t)H_ * V_ * 2);
    f16* h16rec      = (f16*)carve((size_t)(T_ + 1) * B_ * H_ * 2);
    f16* h16log      = (f16*)carve((size_t)B_ * T_ * H_ * 2);
    (void)ws_size; (void)in_sizes; (void)n_in; (void)out_size;

    auto cvt = [&](const float* x, f16* y, size_t n) {
        int n4 = (int)(n / 4);
        hipLaunchKernelGGL(k_cvt_f16, dim3((n4 + 255) / 256), dim3(256), 0, stream, x, y, n4);
    };
    cvt(W_ih, Wih16, (size_t)(E_ + F_) * G4);
    cvt(W_hh, Whh16, (size_t)H_ * G4);
    cvt(W_out, Wout16, (size_t)H_ * V_);
    cvt(image_feats, feats16, (size_t)B_ * L_ * F_);
    hipLaunchKernelGGL(k_emb, dim3(B_ * T_), dim3(E_), 0, stream, embedding, caption, embs16);
    hipLaunchKernelGGL(k_init, dim3(B_), dim3(256), 0, stream,
                       image_feats, W_init_h, b_init_h, W_init_c, b_init_c,
                       hbuf, h16rec, c_cur);
    hipLaunchKernelGGL(k_featproj, dim3(B_ * L_ / 16), dim3(256), 0, stream,
                       image_feats, W_feat, b_feat, featproj);
    // featproj2 = feats @ W_ih[E:,:]   (3136 x 2048, K=512)
    hipLaunchKernelGGL(k_gemm, dim3((B_ * L_ / 64) * (G4 / 64)), dim3(256), 0, stream,
                       feats16, F_, Wih16 + (size_t)E_ * G4, G4,
                       featproj2, G4, F_, G4 / 64, (const float*)nullptr, (const float*)nullptr);
    // embproj = embs @ W_ih[:E,:] + b_ih + b_hh   (2048 x 2048, K=256)
    hipLaunchKernelGGL(k_gemm, dim3((B_ * T_ / 64) * (G4 / 64)), dim3(256), 0, stream,
                       embs16, E_, Wih16, G4,
                       embproj, G4, E_, G4 / 64, b_ih, b_hh);

    for (int t = 0; t < T_; ++t) {
        hipLaunchKernelGGL(k_step_a, dim3(64 + G4 / 64), dim3(256), 0, stream, t,
                           hbuf, h16rec, Whh16, featproj, W_hid, b_hid, W_score, b_score,
                           alpha_ws, out_alpha, hWhh);
        hipLaunchKernelGGL(k_step_b, dim3(B_ * 2), dim3(256), 0, stream, t,
                           embproj, hWhh, alpha_ws, featproj2, c_cur, hbuf, h16rec, h16log);
    }
    // predictions = h16log @ W_out + b_out   (2048 x 32000, K=512)
    hipLaunchKernelGGL(k_gemm, dim3((B_ * T_ / 64) * (V_ / 64)), dim3(256), 0, stream,
                       h16log, H_, Wout16, V_,
                       preds, V_, H_, V_ / 64, b_out, (const float*)nullptr);
}